// Round 5
// baseline (169.263 us; speedup 1.0000x reference)
//
#include <hip/hip_runtime.h>

// SSIM loss — fused separable-conv tile kernel, v5.
// vs v4: packed-fp32 (v_pk_*_f32) over the natural (s,d)=(img1+img2,img1-img2)
// channel pair. LDS staged as interleaved float2, every conv instruction
// processes both channels (ext_vector_type(2) + elementwise_fma -> VOP3P).
// Square-precompute: x-channel h-conv squares the window in place (18 pk_mul)
// then plain fma loop -> h-pass 264->194 packed ops. Groups merged: 1 h-pass,
// 2 work syncs. LDS 39KB -> 4 blocks/CU (occupancy was scheduler-capped ~51%
// anyway at 93% VALUBusy).

typedef float v2f __attribute__((ext_vector_type(2)));

#define IMG   512
#define NIMG  48
#define TW    32
#define TH    32
#define PH    42          // TH + 10
#define SSTR  46          // ssd row stride (v2f units); 46*2%32=28 -> spread b128 starts
#define HSTR  46          // sh2 col stride (v2f units)
#define TILES 16
#define NBLOCKS (NIMG * TILES * TILES)  // 12288

// exp(-(k-5)^2/4.5), unnormalized, symmetric.
#define G0 0.0038659204f
#define G1 0.0285655010f
#define G2 0.1353352832f
#define G3 0.4111123050f
#define G4 0.8007374029f
#define G5 1.0f

__global__ __launch_bounds__(256, 4) void ssim_tile_kernel(
    const float* __restrict__ img1, const float* __restrict__ img2,
    float* __restrict__ partials)
{
    __shared__ v2f ssd[PH][SSTR];        // (s,d) interleaved, 15456 B
    __shared__ v2f sh2[2][TW][HSTR];     // [mu|x][col][row] pairs, 23552 B
    __shared__ float s_part[4];

    const float gw[11] = {G0,G1,G2,G3,G4,G5,G4,G3,G2,G1,G0};

    const int tid = threadIdx.x;
    const int tx0 = blockIdx.x * TW - 5;
    const int ty0 = blockIdx.y * TH - 5;
    const float* __restrict__ p1 = img1 + (size_t)blockIdx.z * (IMG * IMG);
    const float* __restrict__ p2 = img2 + (size_t)blockIdx.z * (IMG * IMG);

    // ---- stage 42x42 of (s,d); incremental row/col (256 = 6*42 + 4) ----
    {
        const bool interior = (blockIdx.x >= 1) && (blockIdx.x <= TILES - 2) &&
                              (blockIdx.y >= 1) && (blockIdx.y <= TILES - 2);
        int r = tid / 42;
        int c = tid - r * 42;
        if (interior) {
#pragma unroll
            for (int it = 0; it < 7; ++it) {
                if (it < 6 || r < PH) {
                    int gi = (ty0 + r) * IMG + (tx0 + c);
                    float a = p1[gi], b = p2[gi];
                    ssd[r][c] = (v2f){a + b, a - b};
                }
                c += 4; r += 6;
                if (c >= 42) { c -= 42; r += 1; }
            }
        } else {
#pragma unroll
            for (int it = 0; it < 7; ++it) {
                if (it < 6 || r < PH) {
                    int gr = ty0 + r, gc = tx0 + c;
                    bool ok = ((unsigned)gr < IMG) && ((unsigned)gc < IMG);
                    int gi = gr * IMG + gc;
                    float a = ok ? p1[gi] : 0.0f;
                    float b = ok ? p2[gi] : 0.0f;
                    ssd[r][c] = (v2f){a + b, a - b};
                }
                c += 4; r += 6;
                if (c >= 42) { c -= 42; r += 1; }
            }
        }
    }

    // h-pass task: 168 active threads, each = (row 0..41) x (8-col group 0..3)
    const bool hact = tid < 168;
    const int  hr  = hact ? (tid % 42) : 0;
    const int  hc0 = hact ? ((tid / 42) * 8) : 0;

    // v-pass mapping: 32 cols x 8 row-groups of 4
    const int col = tid & 31;
    const int r0  = (tid >> 5) * 4;

    __syncthreads();

    // ================= h-pass: both channels packed =================
    if (hact) {
        v2f v[20];
        {
            const float4* src = (const float4*)&ssd[hr][hc0];   // 16B aligned
#pragma unroll
            for (int q = 0; q < 10; ++q) ((float4*)v)[q] = src[q];
        }
        // mu channel: m[j] = sum_k w_k * v[j+k]
        v2f m[8];
#pragma unroll
        for (int j = 0; j < 8; ++j) m[j] = (v2f){0.f, 0.f};
#pragma unroll
        for (int k = 0; k < 11; ++k) {
            const v2f wv = {gw[k], gw[k]};
#pragma unroll
            for (int j = 0; j < 8; ++j)
                m[j] = __builtin_elementwise_fma(v[j + k], wv, m[j]);
        }
#pragma unroll
        for (int j = 0; j < 8; ++j) sh2[0][hc0 + j][hr] = m[j];
        // square window in place, then x channel: x[j] = sum_k w_k * v[j+k]^2
#pragma unroll
        for (int e = 0; e < 18; ++e) v[e] *= v[e];
        v2f x[8];
#pragma unroll
        for (int j = 0; j < 8; ++j) x[j] = (v2f){0.f, 0.f};
#pragma unroll
        for (int k = 0; k < 11; ++k) {
            const v2f wv = {gw[k], gw[k]};
#pragma unroll
            for (int j = 0; j < 8; ++j)
                x[j] = __builtin_elementwise_fma(v[j + k], wv, x[j]);
        }
#pragma unroll
        for (int j = 0; j < 8; ++j) sh2[1][hc0 + j][hr] = x[j];
    }
    __syncthreads();

    // ================= v-pass: packed fma over (s,d) =================
    v2f am[4], ax[4];
    {
        v2f hb[16];
        {
            const float4* s0 = (const float4*)&sh2[0][col][r0];  // 16B aligned
#pragma unroll
            for (int q = 0; q < 8; ++q) ((float4*)hb)[q] = s0[q];
        }
#pragma unroll
        for (int i = 0; i < 4; ++i) {
            v2f s = {0.f, 0.f};
#pragma unroll
            for (int k = 0; k < 11; ++k) {
                const v2f wv = {gw[k], gw[k]};
                s = __builtin_elementwise_fma(wv, hb[i + k], s);
            }
            am[i] = s;
        }
        {
            const float4* s1 = (const float4*)&sh2[1][col][r0];
#pragma unroll
            for (int q = 0; q < 8; ++q) ((float4*)hb)[q] = s1[q];
        }
#pragma unroll
        for (int i = 0; i < 4; ++i) {
            v2f s = {0.f, 0.f};
#pragma unroll
            for (int k = 0; k < 11; ++k) {
                const v2f wv = {gw[k], gw[k]};
                s = __builtin_elementwise_fma(wv, hb[i + k], s);
            }
            ax[i] = s;
        }
    }

    // ---- SSIM from (s,d) algebra ----
    const float C1 = 1.0e-4f, C2 = 9.0e-4f;
    float local = 0.f;
#pragma unroll
    for (int i = 0; i < 4; ++i) {
        v2f mu = am[i];
        v2f mu2 = mu * mu;                   // pk_mul: (ms^2, md^2)
        float sum2 = 0.5f  * (mu2[0] + mu2[1]);   // mu1^2 + mu2^2
        float m12  = 0.25f * (mu2[0] - mu2[1]);   // mu1 * mu2
        v2f xx = ax[i];
        float xsum = 0.5f  * (xx[0] + xx[1]);     // x11 + x22
        float x12  = 0.25f * (xx[0] - xx[1]);
        float sg12  = x12 - m12;
        float sgsum = xsum - sum2;           // sigma1_sq + sigma2_sq
        float num = (2.f * m12 + C1) * (2.f * sg12 + C2);
        float den = (sum2 + C1) * (sgsum + C2);
        local = fmaf(num, __builtin_amdgcn_rcpf(den), local);
    }

#pragma unroll
    for (int off = 32; off > 0; off >>= 1)
        local += __shfl_down(local, off, 64);
    if ((tid & 63) == 0) s_part[tid >> 6] = local;
    __syncthreads();
    if (tid == 0) {
        int bidx = (blockIdx.z * gridDim.y + blockIdx.y) * gridDim.x + blockIdx.x;
        partials[bidx] = s_part[0] + s_part[1] + s_part[2] + s_part[3];
    }
}

__global__ __launch_bounds__(256) void ssim_final_kernel(
    const float* __restrict__ partials, float* __restrict__ out)
{
    __shared__ double sp[4];
    double acc = 0.0;
    for (int i = threadIdx.x; i < NBLOCKS; i += 256)
        acc += (double)partials[i];
#pragma unroll
    for (int off = 32; off > 0; off >>= 1)
        acc += __shfl_down(acc, off, 64);
    if ((threadIdx.x & 63) == 0) sp[threadIdx.x >> 6] = acc;
    __syncthreads();
    if (threadIdx.x == 0) {
        double total = sp[0] + sp[1] + sp[2] + sp[3];
        out[0] = (float)(1.0 - total / (double)((size_t)NIMG * IMG * IMG));
    }
}

extern "C" void kernel_launch(void* const* d_in, const int* in_sizes, int n_in,
                              void* d_out, int out_size, void* d_ws, size_t ws_size,
                              hipStream_t stream) {
    const float* img1 = (const float*)d_in[0];
    const float* img2 = (const float*)d_in[1];
    float* out = (float*)d_out;
    float* partials = (float*)d_ws;   // NBLOCKS floats, fully rewritten each call

    dim3 grid(TILES, TILES, NIMG);
    ssim_tile_kernel<<<grid, dim3(256), 0, stream>>>(img1, img2, partials);
    ssim_final_kernel<<<1, dim3(256), 0, stream>>>(partials, out);
}